// Round 12
// baseline (1082.259 us; speedup 1.0000x reference)
//
#include <hip/hip_runtime.h>

#define NEG 0.01f
__device__ __forceinline__ float lrelu(float v){ return v >= 0.f ? v : NEG * v; }

__device__ __forceinline__ float fma4(float4 wv, float4 hv, float acc) {
  return fmaf(wv.x, hv.x, fmaf(wv.y, hv.y, fmaf(wv.z, hv.z, fmaf(wv.w, hv.w, acc))));
}

// ---- LDS plan: single arena S[8192] (32768 B) ----
// Phase A (0-4a): XS@0(121, dies stage-1) | SB@0(2916, born 2a) | H2@2916(81x64)
// Phase B (4b-5): HROW@0(64x108=6912); stage-5 computes from HROW with NO LDS
//                 writes, then (barrier) partials P5@0(4x32x49=6272) overwrite
//                 dead HROW, (barrier) reduce -> C2S@6272(32x56=1792, ends 8064)
// Phase C (6+):   P6@0(1600) C3S@3392(200) D1P@3600(256) D1@3856 D2@3920
//                 D3@3952 D4@3968  [all in dead P5; C2S@6272 read by stage 6]
// RULES:
//  (R2) no runtime-bound loop may index a register array — full unroll +
//       per-iteration predicate only (violation = 810 MB scratch traffic).
//  (R5) do NOT tighten __launch_bounds__ to (256,4): VGPR force-cap 64 -> spills.
//  (R7) do NOT split stage-5 partials per-(oc,yy) through LDS (lost 8%).
//  (R8) fuse T/P/G in one H2 pass; carry G in regs across softmax barrier.
//  (R9) dense head in wave 0 only (s_waitcnt+wave_barrier ordering).
//  (R10) 32768 B arena = 5-blocks/CU LDS cliff; VGPR must stay <=64 for 20 waves.
//  (R11) stage-5 (oc,icg) mapping: weights read 1x, all 256 threads busy;
//        shfl_xor(32) + one LDS round-trip for the icg reduction.
//  (R12) stage-5 runs in two row-bands (acc 28 then 21) so peak live regs
//        fit the 64-VGPR budget — 49 live accs forced hidden AGPR shuffling.
#define XS   0
#define SB   0
#define H2   2916
#define HROW 0
#define P5   0
#define C2S  6272
#define P6   0
#define C3S  3392
#define D1P  3600
#define D1   3856
#define D2   3920
#define D3   3952
#define D4   3968

// repack: w2 [oc32][ic64][9] -> pw2 [ic64][oc32][12] (pad3);
//         w3 [oc8][ic32][9]  -> pw3 [ic32][oc8][12]  (pad3, at +24576 floats)
__global__ void repack_w23(const float* __restrict__ w2, const float* __restrict__ w3,
                           float* __restrict__ pw) {
  int idx = blockIdx.x * 256 + threadIdx.x;
  for (int i = idx; i < 64 * 32 * 12 + 32 * 8 * 12; i += gridDim.x * 256) {
    if (i < 64 * 32 * 12) {
      int s = i % 12, rest = i / 12, oc = rest & 31, ic = rest >> 5;
      pw[i] = (s < 9) ? w2[(oc * 64 + ic) * 9 + s] : 0.f;
    } else {
      int j = i - 64 * 32 * 12;
      int s = j % 12, rest = j / 12, oc = rest & 7, ic = rest >> 3;
      pw[i] = (s < 9) ? w3[(oc * 32 + ic) * 9 + s] : 0.f;
    }
  }
}

__global__ __launch_bounds__(256, 3) void braggnn_fused(
    const float* __restrict__ x,
    const float* __restrict__ w1, const float* __restrict__ b1,
    const float* __restrict__ wt, const float* __restrict__ bt,
    const float* __restrict__ wp, const float* __restrict__ bp,
    const float* __restrict__ wg, const float* __restrict__ bg,
    const float* __restrict__ wo, const float* __restrict__ bo,
    const float* __restrict__ pw2, const float* __restrict__ pw3,
    const float* __restrict__ b2,
    const float* __restrict__ b3,
    const float* __restrict__ dw1, const float* __restrict__ db1,
    const float* __restrict__ dw2, const float* __restrict__ db2,
    const float* __restrict__ dw3, const float* __restrict__ db3,
    const float* __restrict__ dw4, const float* __restrict__ db4,
    const float* __restrict__ dw5, const float* __restrict__ db5,
    float* __restrict__ out)
{
  const int b = blockIdx.x;
  const int t = threadIdx.x;

  __shared__ __align__(16) float S[8192];   // 32768 B

  // ---- stage 0: load 11x11 patch ----
  if (t < 121) S[XS + t] = x[(size_t)b * 121 + t];
  __syncthreads();

  // ---- stage 1: conv1 1->64 3x3 -> H2[px][oc] ch-major stride 64 (no act) ----
  {
    const int oc = t & 63, pg = t >> 6;
    float wreg[9];
#pragma unroll
    for (int i = 0; i < 9; i++) wreg[i] = w1[oc * 9 + i];
    const float bv = b1[oc];
    for (int px = pg; px < 81; px += 4) {
      const int y = px / 9, xx = px - y * 9;
      const float* xr = &S[XS + y * 11 + xx];
      float a = bv;
#pragma unroll
      for (int ky = 0; ky < 3; ky++)
#pragma unroll
        for (int kx = 0; kx < 3; kx++)
          a = fmaf(xr[ky * 11 + kx], wreg[ky * 3 + kx], a);
      S[H2 + px * 64 + oc] = a;
    }
  }
  __syncthreads();

  // ---- stage 2 pass A: fused theta/phi/g GEMM, ONE H2 read ----
  float gReg[10];
  float g80 = 0.f;
  {
    const int oc = t & 31, pxb = t >> 5;
    const float4* wt4 = (const float4*)wt;
    const float4* wp4 = (const float4*)wp;
    const float4* wg4 = (const float4*)wg;
    float aT[10] = {0,0,0,0,0,0,0,0,0,0};
    float aP[10] = {0,0,0,0,0,0,0,0,0,0};
    float aG[10] = {0,0,0,0,0,0,0,0,0,0};
#pragma unroll 2
    for (int k4 = 0; k4 < 16; k4++) {
      const float4 wT = wt4[oc * 16 + k4];
      const float4 wP = wp4[oc * 16 + k4];
      const float4 wG = wg4[oc * 16 + k4];
#pragma unroll
      for (int i = 0; i < 10; i++) {
        const float4 hv = *(const float4*)&S[H2 + (pxb + 8 * i) * 64 + k4 * 4];
        aT[i] = fma4(wT, hv, aT[i]);
        aP[i] = fma4(wP, hv, aP[i]);
        aG[i] = fma4(wG, hv, aG[i]);
      }
    }
    const float bT = bt[oc], bP = bp[oc], bG = bg[oc];
#pragma unroll
    for (int i = 0; i < 10; i++) {
      S[SB + (pxb + 8 * i) * 36 + oc] = (aT[i] + bT) * (aP[i] + bP);
      gReg[i] = aG[i] + bG;
    }
    if (t < 32) {          // px = 80 leftover: oc = t
      float aT8 = 0.f, aP8 = 0.f, aG8 = 0.f;
#pragma unroll 2
      for (int k4 = 0; k4 < 16; k4++) {
        const float4 hv = *(const float4*)&S[H2 + 80 * 64 + k4 * 4];
        aT8 = fma4(wt4[t * 16 + k4], hv, aT8);
        aP8 = fma4(wp4[t * 16 + k4], hv, aP8);
        aG8 = fma4(wg4[t * 16 + k4], hv, aG8);
      }
      S[SB + 80 * 36 + t] = (aT8 + bt[t]) * (aP8 + bp[t]);
      g80 = aG8 + bg[t];
    }
  }
  __syncthreads();

  // ---- stage 2 pass B: softmax over W (9) in place on SB ----
  {
    auto sm = [&](int r) {
      const int oc = r & 31, y = r >> 5;
      const int base = SB + y * 9 * 36 + oc;
      float v[9]; float m = -1e30f;
#pragma unroll
      for (int k = 0; k < 9; k++) { v[k] = S[base + k * 36]; m = fmaxf(m, v[k]); }
      float s = 0.f;
#pragma unroll
      for (int k = 0; k < 9; k++) { v[k] = __expf(v[k] - m); s += v[k]; }
      const float inv = 1.f / s;
#pragma unroll
      for (int k = 0; k < 9; k++) S[base + k * 36] = v[k] * inv;
    };
    sm(t);
    if (t < 32) sm(256 + t);
  }
  __syncthreads();

  // ---- stage 2 pass C: SB = attn * G (G from registers, in place) ----
  {
    const int oc = t & 31, pxb = t >> 5;
#pragma unroll
    for (int i = 0; i < 10; i++) {
      const int idx = SB + (pxb + 8 * i) * 36 + oc;
      S[idx] = gReg[i] * S[idx];
    }
    if (t < 32) {
      const int idx = SB + 80 * 36 + t;
      S[idx] = g80 * S[idx];
    }
  }
  __syncthreads();

  // ---- stage 4: wo 1x1 (32->64) + residual + lrelu -> HROW [oc][9][12] ----
  {
    const int ocq = t >> 4, q = t & 15;
    const int oc0 = ocq * 4;
    int pxs[6];
#pragma unroll
    for (int j = 0; j < 6; j++) { int p = q + 16 * j; pxs[j] = (p > 80) ? 80 : p; }
    float a0[6] = {0,0,0,0,0,0}, a1[6] = {0,0,0,0,0,0};
    float a2[6] = {0,0,0,0,0,0}, a3[6] = {0,0,0,0,0,0};
    const float4* wo4 = (const float4*)wo;
#pragma unroll 4
    for (int k4 = 0; k4 < 8; k4++) {
      const float4 u0 = wo4[(oc0 + 0) * 8 + k4];
      const float4 u1 = wo4[(oc0 + 1) * 8 + k4];
      const float4 u2 = wo4[(oc0 + 2) * 8 + k4];
      const float4 u3 = wo4[(oc0 + 3) * 8 + k4];
#pragma unroll
      for (int j = 0; j < 6; j++) {
        const float4 gv = *(const float4*)&S[SB + pxs[j] * 36 + k4 * 4];
        a0[j] = fma4(u0, gv, a0[j]); a1[j] = fma4(u1, gv, a1[j]);
        a2[j] = fma4(u2, gv, a2[j]); a3[j] = fma4(u3, gv, a3[j]);
      }
    }
    // residual pre-read (H2/SB die at the sync; HROW aliases them)
    float4 hres[6];
#pragma unroll
    for (int j = 0; j < 6; j++)
      hres[j] = *(const float4*)&S[H2 + pxs[j] * 64 + oc0];
    __syncthreads();
    const float bo0 = bo[oc0], bo1 = bo[oc0 + 1], bo2 = bo[oc0 + 2], bo3 = bo[oc0 + 3];
#pragma unroll
    for (int j = 0; j < 6; j++) {
      if (q + 16 * j <= 80) {   // unique-write predicate, compile-time unrolled
        const int px = pxs[j];
        const int y = px / 9, xx = px - y * 9;
        const int ro = y * 12 + xx;
        S[HROW + (oc0 + 0) * 108 + ro] = lrelu(hres[j].x + a0[j] + bo0);
        S[HROW + (oc0 + 1) * 108 + ro] = lrelu(hres[j].y + a1[j] + bo1);
        S[HROW + (oc0 + 2) * 108 + ro] = lrelu(hres[j].z + a2[j] + bo2);
        S[HROW + (oc0 + 3) * 108 + ro] = lrelu(hres[j].w + a3[j] + bo3);
      }
    }
  }
  __syncthreads();

  // ---- stage 5 (R12): conv2 64->32 3x3, thread=(oc, icg8), two row-bands ----
  {
    const int oc = t & 31, icg = t >> 5;
    const float4* pw4 = (const float4*)pw2;

    // band A: out rows 0-3 (28 acc), input rows 0-5
    float accA[4][7] = {{0,0,0,0,0,0,0},{0,0,0,0,0,0,0},
                        {0,0,0,0,0,0,0},{0,0,0,0,0,0,0}};
    for (int i8 = 0; i8 < 8; i8++) {
      const int ic = icg * 8 + i8;
      const float4 f0 = pw4[(ic * 32 + oc) * 3 + 0];
      const float4 f1 = pw4[(ic * 32 + oc) * 3 + 1];
      const float4 f2 = pw4[(ic * 32 + oc) * 3 + 2];
      const float w[9] = {f0.x, f0.y, f0.z, f0.w, f1.x, f1.y, f1.z, f1.w, f2.x};
      const int hb = HROW + ic * 108;
#pragma unroll
      for (int r = 0; r < 6; r++) {
        const float4* rp = (const float4*)&S[hb + r * 12];
        const float4 ra = rp[0], rb = rp[1], rc = rp[2];
        const float row[12] = {ra.x, ra.y, ra.z, ra.w, rb.x, rb.y, rb.z, rb.w,
                               rc.x, rc.y, rc.z, rc.w};
#pragma unroll
        for (int ky = 0; ky < 3; ky++) {
          const int yy = r - ky;               // compile-time after unroll
          if (yy >= 0 && yy <= 3) {
#pragma unroll
            for (int xx = 0; xx < 7; xx++)
              accA[yy][xx] = fmaf(row[xx],     w[ky * 3 + 0],
                             fmaf(row[xx + 1], w[ky * 3 + 1],
                             fmaf(row[xx + 2], w[ky * 3 + 2], accA[yy][xx])));
          }
        }
      }
    }

    // band B: out rows 4-6 (21 acc), input rows 4-8
    float accB[3][7] = {{0,0,0,0,0,0,0},{0,0,0,0,0,0,0},{0,0,0,0,0,0,0}};
    for (int i8 = 0; i8 < 8; i8++) {
      const int ic = icg * 8 + i8;
      const float4 f0 = pw4[(ic * 32 + oc) * 3 + 0];
      const float4 f1 = pw4[(ic * 32 + oc) * 3 + 1];
      const float4 f2 = pw4[(ic * 32 + oc) * 3 + 2];
      const float w[9] = {f0.x, f0.y, f0.z, f0.w, f1.x, f1.y, f1.z, f1.w, f2.x};
      const int hb = HROW + ic * 108;
#pragma unroll
      for (int r = 4; r < 9; r++) {
        const float4* rp = (const float4*)&S[hb + r * 12];
        const float4 ra = rp[0], rb = rp[1], rc = rp[2];
        const float row[12] = {ra.x, ra.y, ra.z, ra.w, rb.x, rb.y, rb.z, rb.w,
                               rc.x, rc.y, rc.z, rc.w};
#pragma unroll
        for (int ky = 0; ky < 3; ky++) {
          const int yy = r - ky;
          if (yy >= 4 && yy <= 6) {
#pragma unroll
            for (int xx = 0; xx < 7; xx++)
              accB[yy - 4][xx] = fmaf(row[xx],     w[ky * 3 + 0],
                                 fmaf(row[xx + 1], w[ky * 3 + 1],
                                 fmaf(row[xx + 2], w[ky * 3 + 2], accB[yy - 4][xx])));
          }
        }
      }
    }

    // pair-reduce icg halves within the wave (lane ^ 32)
#pragma unroll
    for (int yy = 0; yy < 4; yy++)
#pragma unroll
      for (int xx = 0; xx < 7; xx++)
        accA[yy][xx] += __shfl_xor(accA[yy][xx], 32, 64);
#pragma unroll
    for (int yy = 0; yy < 3; yy++)
#pragma unroll
      for (int xx = 0; xx < 7; xx++)
        accB[yy][xx] += __shfl_xor(accB[yy][xx], 32, 64);
    __syncthreads();                 // HROW fully consumed; P5 overwrites it
    const int wv = t >> 6;
    if ((t & 63) < 32) {
      float* pp = &S[P5 + (wv * 32 + oc) * 49];
#pragma unroll
      for (int yy = 0; yy < 4; yy++)
#pragma unroll
        for (int xx = 0; xx < 7; xx++)
          pp[yy * 7 + xx] = accA[yy][xx];
#pragma unroll
      for (int yy = 0; yy < 3; yy++)
#pragma unroll
        for (int xx = 0; xx < 7; xx++)
          pp[(yy + 4) * 7 + xx] = accB[yy][xx];
    }
  }
  __syncthreads();
  // reduce 4 wave-partials -> C2S [32][7][8] (+bias, lrelu)
  {
#pragma unroll
    for (int r = 0; r < 7; r++) {
      const int o = t + 256 * r;
      if (o < 1568) {
        const int oc = o / 49, pos = o - oc * 49;
        const int yy = pos / 7, xx = pos - yy * 7;
        const float s = b2[oc]
            + S[P5 + oc * 49 + pos]        + S[P5 + (32 + oc) * 49 + pos]
            + S[P5 + (64 + oc) * 49 + pos] + S[P5 + (96 + oc) * 49 + pos];
        S[C2S + oc * 56 + yy * 8 + xx] = lrelu(s);
      }
    }
  }
  __syncthreads();

  // ---- stage 6: conv3 32->8 3x3, K split in 8 groups of 4 ic, pw3 f4 loads ----
  {
    const int px = t & 31, ic8 = t >> 5;
    if (px < 25) {
      const int y = px / 5, xx = px - y * 5;
      float p[8] = {0,0,0,0,0,0,0,0};
      const float4* pw34 = (const float4*)pw3;
#pragma unroll
      for (int i = 0; i < 4; i++) {
        const int icg = ic8 * 4 + i;
        float rr[9];
#pragma unroll
        for (int ky = 0; ky < 3; ky++) {
          const int base = C2S + icg * 56 + (y + ky) * 8 + xx;
          rr[ky * 3 + 0] = S[base];
          rr[ky * 3 + 1] = S[base + 1];
          rr[ky * 3 + 2] = S[base + 2];
        }
#pragma unroll
        for (int oc = 0; oc < 8; oc++) {
          const float4 f0 = pw34[(icg * 8 + oc) * 3 + 0];
          const float4 f1 = pw34[(icg * 8 + oc) * 3 + 1];
          const float4 f2 = pw34[(icg * 8 + oc) * 3 + 2];
          p[oc] = fmaf(rr[0], f0.x, fmaf(rr[1], f0.y, fmaf(rr[2], f0.z,
                  fmaf(rr[3], f0.w, fmaf(rr[4], f1.x, fmaf(rr[5], f1.y,
                  fmaf(rr[6], f1.z, fmaf(rr[7], f1.w, fmaf(rr[8], f2.x, p[oc])))))))));
        }
      }
      float* wpp = &S[P6 + px * 64 + ic8 * 8];
#pragma unroll
      for (int oc = 0; oc < 8; oc++) wpp[oc] = p[oc];
    }
  }
  __syncthreads();
  if (t < 200) {
    const int oc = t & 7, px = t >> 3;
    float s = b3[oc];
    const float* rp = &S[P6 + px * 64 + oc];
#pragma unroll
    for (int g = 0; g < 8; g++) s += rp[g * 8];
    S[C3S + oc * 25 + px] = lrelu(s);
  }
  __syncthreads();

  // ---- stage 7: dense 200->64 partials, 4 chunks (56/56/56/32), float4 ----
  {
    const int o = t & 63, chunk = t >> 6;
    const int start = chunk * 56;
    const int cnt = (chunk == 3) ? 8 : 14;
    const float4* wr4 = (const float4*)&dw1[o * 200 + start];
    const float4* cr4 = (const float4*)&S[C3S + start];
    float acc = 0.f;
    for (int i = 0; i < cnt; i++) {   // runtime bound OK: memory only
      const float4 wv = wr4[i], cv = cr4[i];
      acc += wv.x * cv.x + wv.y * cv.y + wv.z * cv.z + wv.w * cv.w;
    }
    S[D1P + chunk * 64 + o] = acc;
  }
  __syncthreads();

  // ---- dense head: wave 0 only, no workgroup barriers (waves 1-3 retire) ----
  if (t < 64) {
    S[D1 + t] = lrelu(S[D1P + t] + S[D1P + 64 + t] + S[D1P + 128 + t] +
                      S[D1P + 192 + t] + db1[t]);
    __builtin_amdgcn_s_waitcnt(0); __builtin_amdgcn_wave_barrier();
    if (t < 32) {
      float acc = db2[t];
      const float4* wr = (const float4*)&dw2[t * 64];
      const float4* dr = (const float4*)&S[D1];
#pragma unroll
      for (int i = 0; i < 16; i++) acc = fma4(wr[i], dr[i], acc);
      S[D2 + t] = lrelu(acc);
    }
    __builtin_amdgcn_s_waitcnt(0); __builtin_amdgcn_wave_barrier();
    if (t < 16) {
      float acc = db3[t];
      const float4* wr = (const float4*)&dw3[t * 32];
      const float4* dr = (const float4*)&S[D2];
#pragma unroll
      for (int i = 0; i < 8; i++) acc = fma4(wr[i], dr[i], acc);
      S[D3 + t] = lrelu(acc);
    }
    __builtin_amdgcn_s_waitcnt(0); __builtin_amdgcn_wave_barrier();
    if (t < 8) {
      float acc = db4[t];
      const float4* wr = (const float4*)&dw4[t * 16];
      const float4* dr = (const float4*)&S[D3];
#pragma unroll
      for (int i = 0; i < 4; i++) acc = fma4(wr[i], dr[i], acc);
      S[D4 + t] = lrelu(acc);
    }
    __builtin_amdgcn_s_waitcnt(0); __builtin_amdgcn_wave_barrier();
    if (t < 2) {
      float acc = db5[t];
      const float4* wr = (const float4*)&dw5[t * 8];
      const float4* dr = (const float4*)&S[D4];
#pragma unroll
      for (int i = 0; i < 2; i++) acc = fma4(wr[i], dr[i], acc);
      out[(size_t)b * 2 + t] = acc;
    }
  }
}

extern "C" void kernel_launch(void* const* d_in, const int* in_sizes, int n_in,
                              void* d_out, int out_size, void* d_ws, size_t ws_size,
                              hipStream_t stream) {
  const float* x   = (const float*)d_in[0];
  const float* w1  = (const float*)d_in[1];
  const float* b1  = (const float*)d_in[2];
  const float* wt  = (const float*)d_in[3];
  const float* bt  = (const float*)d_in[4];
  const float* wp  = (const float*)d_in[5];
  const float* bp  = (const float*)d_in[6];
  const float* wg  = (const float*)d_in[7];
  const float* bg  = (const float*)d_in[8];
  const float* wo  = (const float*)d_in[9];
  const float* bo  = (const float*)d_in[10];
  const float* w2  = (const float*)d_in[11];
  const float* b2  = (const float*)d_in[12];
  const float* w3  = (const float*)d_in[13];
  const float* b3  = (const float*)d_in[14];
  const float* dw1 = (const float*)d_in[15];
  const float* db1 = (const float*)d_in[16];
  const float* dw2 = (const float*)d_in[17];
  const float* db2 = (const float*)d_in[18];
  const float* dw3 = (const float*)d_in[19];
  const float* db3 = (const float*)d_in[20];
  const float* dw4 = (const float*)d_in[21];
  const float* db4 = (const float*)d_in[22];
  const float* dw5 = (const float*)d_in[23];
  const float* db5 = (const float*)d_in[24];

  float* pw = (float*)d_ws;             // pw2: 24576 floats, pw3: 3072 floats
  repack_w23<<<32, 256, 0, stream>>>(w2, w3, pw);
  const float* pw2 = pw;
  const float* pw3 = pw + 24576;

  int B = in_sizes[0] / 121;
  braggnn_fused<<<B, 256, 0, stream>>>(
      x, w1, b1, wt, bt, wp, bp, wg, bg, wo, bo, pw2, pw3, b2, b3,
      dw1, db1, dw2, db2, dw3, db3, dw4, db4, dw5, db5,
      (float*)d_out);
}

// Round 13
// 1046.600 us; speedup vs baseline: 1.0341x; 1.0341x over previous
//
#include <hip/hip_runtime.h>

#define NEG 0.01f
__device__ __forceinline__ float lrelu(float v){ return v >= 0.f ? v : NEG * v; }

typedef float v2f __attribute__((ext_vector_type(2)));

__device__ __forceinline__ float fma4(float4 wv, float4 hv, float acc) {
  return fmaf(wv.x, hv.x, fmaf(wv.y, hv.y, fmaf(wv.z, hv.z, fmaf(wv.w, hv.w, acc))));
}

// ---- LDS plan: single arena S[8192] (32768 B) ----
// Phase A (0-4a): XS@0(121, dies stage-1) | SB@0(2916, born 2a) | H2@2916(81x64)
// Phase B (4b-5): HROW@0(64x108=6912); stage-5 computes from HROW with NO LDS
//                 writes, then (barrier) partials P5@0(4x32x49=6272) overwrite
//                 dead HROW, (barrier) reduce -> C2S@6272(32x56=1792, ends 8064)
// Phase C (6+):   P6@0(1600) C3S@3392(200) D1P@3600(256) D1@3856 D2@3920
//                 D3@3952 D4@3968  [all in dead P5; C2S@6272 read by stage 6]
// RULES:
//  (R2)  no runtime-bound loop may index a register array — full unroll +
//        per-iteration predicate only (violation = 810 MB scratch traffic).
//  (R5)  do NOT tighten __launch_bounds__ to (256,4): VGPR force-cap 64 -> spills.
//  (R7)  do NOT split stage-5 partials per-(oc,yy) through LDS (lost 8%).
//  (R8)  fuse T/P/G in one H2 pass; carry G in regs across softmax barrier.
//  (R9)  dense head in wave 0 only (s_waitcnt+wave_barrier ordering).
//  (R10) 32768 B arena = 5-blocks/CU LDS cliff; VGPR must stay <=64 for 20 waves.
//  (R11) stage-5 (oc,icg) single-pass acc[7][7]: weights read 1x, 256 threads
//        busy; shfl_xor(32) + one LDS round-trip. KEEP EXACTLY THIS FORM:
//  (R12) two-row-band variant of stage 5 regressed 3% (extra reads/loop
//        overhead; no hidden spill tax existed at VGPR=64).
//  (R13) stage-2a packs theta+phi via v2f fma (v_pk_fma_f32): {wT,wP}x{h,h};
//        acc storage unchanged. P5-reduce is div-free (oc,yy,xx from bits).
#define XS   0
#define SB   0
#define H2   2916
#define HROW 0
#define P5   0
#define C2S  6272
#define P6   0
#define C3S  3392
#define D1P  3600
#define D1   3856
#define D2   3920
#define D3   3952
#define D4   3968

// repack: w2 [oc32][ic64][9] -> pw2 [ic64][oc32][12] (pad3);
//         w3 [oc8][ic32][9]  -> pw3 [ic32][oc8][12]  (pad3, at +24576 floats)
__global__ void repack_w23(const float* __restrict__ w2, const float* __restrict__ w3,
                           float* __restrict__ pw) {
  int idx = blockIdx.x * 256 + threadIdx.x;
  for (int i = idx; i < 64 * 32 * 12 + 32 * 8 * 12; i += gridDim.x * 256) {
    if (i < 64 * 32 * 12) {
      int s = i % 12, rest = i / 12, oc = rest & 31, ic = rest >> 5;
      pw[i] = (s < 9) ? w2[(oc * 64 + ic) * 9 + s] : 0.f;
    } else {
      int j = i - 64 * 32 * 12;
      int s = j % 12, rest = j / 12, oc = rest & 7, ic = rest >> 3;
      pw[i] = (s < 9) ? w3[(oc * 32 + ic) * 9 + s] : 0.f;
    }
  }
}

__global__ __launch_bounds__(256, 3) void braggnn_fused(
    const float* __restrict__ x,
    const float* __restrict__ w1, const float* __restrict__ b1,
    const float* __restrict__ wt, const float* __restrict__ bt,
    const float* __restrict__ wp, const float* __restrict__ bp,
    const float* __restrict__ wg, const float* __restrict__ bg,
    const float* __restrict__ wo, const float* __restrict__ bo,
    const float* __restrict__ pw2, const float* __restrict__ pw3,
    const float* __restrict__ b2,
    const float* __restrict__ b3,
    const float* __restrict__ dw1, const float* __restrict__ db1,
    const float* __restrict__ dw2, const float* __restrict__ db2,
    const float* __restrict__ dw3, const float* __restrict__ db3,
    const float* __restrict__ dw4, const float* __restrict__ db4,
    const float* __restrict__ dw5, const float* __restrict__ db5,
    float* __restrict__ out)
{
  const int b = blockIdx.x;
  const int t = threadIdx.x;

  __shared__ __align__(16) float S[8192];   // 32768 B

  // ---- stage 0: load 11x11 patch ----
  if (t < 121) S[XS + t] = x[(size_t)b * 121 + t];
  __syncthreads();

  // ---- stage 1: conv1 1->64 3x3 -> H2[px][oc] ch-major stride 64 (no act) ----
  {
    const int oc = t & 63, pg = t >> 6;
    float wreg[9];
#pragma unroll
    for (int i = 0; i < 9; i++) wreg[i] = w1[oc * 9 + i];
    const float bv = b1[oc];
    for (int px = pg; px < 81; px += 4) {
      const int y = px / 9, xx = px - y * 9;
      const float* xr = &S[XS + y * 11 + xx];
      float a = bv;
#pragma unroll
      for (int ky = 0; ky < 3; ky++)
#pragma unroll
        for (int kx = 0; kx < 3; kx++)
          a = fmaf(xr[ky * 11 + kx], wreg[ky * 3 + kx], a);
      S[H2 + px * 64 + oc] = a;
    }
  }
  __syncthreads();

  // ---- stage 2 pass A (R13): fused theta/phi packed + g, ONE H2 read ----
  float gReg[10];
  float g80 = 0.f;
  {
    const int oc = t & 31, pxb = t >> 5;
    const float4* wt4 = (const float4*)wt;
    const float4* wp4 = (const float4*)wp;
    const float4* wg4 = (const float4*)wg;
    v2f aTP[10];
#pragma unroll
    for (int i = 0; i < 10; i++) aTP[i] = (v2f){0.f, 0.f};
    float aG[10] = {0,0,0,0,0,0,0,0,0,0};
#pragma unroll 2
    for (int k4 = 0; k4 < 16; k4++) {
      const float4 wT = wt4[oc * 16 + k4];
      const float4 wP = wp4[oc * 16 + k4];
      const float4 wG = wg4[oc * 16 + k4];
      const v2f wtp0 = {wT.x, wP.x}, wtp1 = {wT.y, wP.y};
      const v2f wtp2 = {wT.z, wP.z}, wtp3 = {wT.w, wP.w};
#pragma unroll
      for (int i = 0; i < 10; i++) {
        const float4 hv = *(const float4*)&S[H2 + (pxb + 8 * i) * 64 + k4 * 4];
        aTP[i] = __builtin_elementwise_fma(wtp0, (v2f){hv.x, hv.x}, aTP[i]);
        aTP[i] = __builtin_elementwise_fma(wtp1, (v2f){hv.y, hv.y}, aTP[i]);
        aTP[i] = __builtin_elementwise_fma(wtp2, (v2f){hv.z, hv.z}, aTP[i]);
        aTP[i] = __builtin_elementwise_fma(wtp3, (v2f){hv.w, hv.w}, aTP[i]);
        aG[i] = fma4(wG, hv, aG[i]);
      }
    }
    const float bT = bt[oc], bP = bp[oc], bG = bg[oc];
#pragma unroll
    for (int i = 0; i < 10; i++) {
      S[SB + (pxb + 8 * i) * 36 + oc] = (aTP[i].x + bT) * (aTP[i].y + bP);
      gReg[i] = aG[i] + bG;
    }
    if (t < 32) {          // px = 80 leftover: oc = t
      float aT8 = 0.f, aP8 = 0.f, aG8 = 0.f;
#pragma unroll 2
      for (int k4 = 0; k4 < 16; k4++) {
        const float4 hv = *(const float4*)&S[H2 + 80 * 64 + k4 * 4];
        aT8 = fma4(wt4[t * 16 + k4], hv, aT8);
        aP8 = fma4(wp4[t * 16 + k4], hv, aP8);
        aG8 = fma4(wg4[t * 16 + k4], hv, aG8);
      }
      S[SB + 80 * 36 + t] = (aT8 + bt[t]) * (aP8 + bp[t]);
      g80 = aG8 + bg[t];
    }
  }
  __syncthreads();

  // ---- stage 2 pass B: softmax over W (9) in place on SB ----
  {
    auto sm = [&](int r) {
      const int oc = r & 31, y = r >> 5;
      const int base = SB + y * 9 * 36 + oc;
      float v[9]; float m = -1e30f;
#pragma unroll
      for (int k = 0; k < 9; k++) { v[k] = S[base + k * 36]; m = fmaxf(m, v[k]); }
      float s = 0.f;
#pragma unroll
      for (int k = 0; k < 9; k++) { v[k] = __expf(v[k] - m); s += v[k]; }
      const float inv = 1.f / s;
#pragma unroll
      for (int k = 0; k < 9; k++) S[base + k * 36] = v[k] * inv;
    };
    sm(t);
    if (t < 32) sm(256 + t);
  }
  __syncthreads();

  // ---- stage 2 pass C: SB = attn * G (G from registers, in place) ----
  {
    const int oc = t & 31, pxb = t >> 5;
#pragma unroll
    for (int i = 0; i < 10; i++) {
      const int idx = SB + (pxb + 8 * i) * 36 + oc;
      S[idx] = gReg[i] * S[idx];
    }
    if (t < 32) {
      const int idx = SB + 80 * 36 + t;
      S[idx] = g80 * S[idx];
    }
  }
  __syncthreads();

  // ---- stage 4: wo 1x1 (32->64) + residual + lrelu -> HROW [oc][9][12] ----
  {
    const int ocq = t >> 4, q = t & 15;
    const int oc0 = ocq * 4;
    int pxs[6];
#pragma unroll
    for (int j = 0; j < 6; j++) { int p = q + 16 * j; pxs[j] = (p > 80) ? 80 : p; }
    float a0[6] = {0,0,0,0,0,0}, a1[6] = {0,0,0,0,0,0};
    float a2[6] = {0,0,0,0,0,0}, a3[6] = {0,0,0,0,0,0};
    const float4* wo4 = (const float4*)wo;
#pragma unroll 4
    for (int k4 = 0; k4 < 8; k4++) {
      const float4 u0 = wo4[(oc0 + 0) * 8 + k4];
      const float4 u1 = wo4[(oc0 + 1) * 8 + k4];
      const float4 u2 = wo4[(oc0 + 2) * 8 + k4];
      const float4 u3 = wo4[(oc0 + 3) * 8 + k4];
#pragma unroll
      for (int j = 0; j < 6; j++) {
        const float4 gv = *(const float4*)&S[SB + pxs[j] * 36 + k4 * 4];
        a0[j] = fma4(u0, gv, a0[j]); a1[j] = fma4(u1, gv, a1[j]);
        a2[j] = fma4(u2, gv, a2[j]); a3[j] = fma4(u3, gv, a3[j]);
      }
    }
    // residual pre-read (H2/SB die at the sync; HROW aliases them)
    float4 hres[6];
#pragma unroll
    for (int j = 0; j < 6; j++)
      hres[j] = *(const float4*)&S[H2 + pxs[j] * 64 + oc0];
    __syncthreads();
    const float bo0 = bo[oc0], bo1 = bo[oc0 + 1], bo2 = bo[oc0 + 2], bo3 = bo[oc0 + 3];
#pragma unroll
    for (int j = 0; j < 6; j++) {
      if (q + 16 * j <= 80) {   // unique-write predicate, compile-time unrolled
        const int px = pxs[j];
        const int y = px / 9, xx = px - y * 9;
        const int ro = y * 12 + xx;
        S[HROW + (oc0 + 0) * 108 + ro] = lrelu(hres[j].x + a0[j] + bo0);
        S[HROW + (oc0 + 1) * 108 + ro] = lrelu(hres[j].y + a1[j] + bo1);
        S[HROW + (oc0 + 2) * 108 + ro] = lrelu(hres[j].z + a2[j] + bo2);
        S[HROW + (oc0 + 3) * 108 + ro] = lrelu(hres[j].w + a3[j] + bo3);
      }
    }
  }
  __syncthreads();

  // ---- stage 5 (R11 form): conv2 64->32 3x3, thread=(oc, icg8), acc[7][7] ----
  {
    const int oc = t & 31, icg = t >> 5;
    float acc[7][7] = {{0,0,0,0,0,0,0},{0,0,0,0,0,0,0},{0,0,0,0,0,0,0},
                       {0,0,0,0,0,0,0},{0,0,0,0,0,0,0},{0,0,0,0,0,0,0},
                       {0,0,0,0,0,0,0}};
    const float4* pw4 = (const float4*)pw2;
    for (int i8 = 0; i8 < 8; i8++) {      // runtime bound OK: memory + const-idx locals
      const int ic = icg * 8 + i8;
      const float4 f0 = pw4[(ic * 32 + oc) * 3 + 0];
      const float4 f1 = pw4[(ic * 32 + oc) * 3 + 1];
      const float4 f2 = pw4[(ic * 32 + oc) * 3 + 2];
      const float w[9] = {f0.x, f0.y, f0.z, f0.w, f1.x, f1.y, f1.z, f1.w, f2.x};
      const int hb = HROW + ic * 108;
#pragma unroll
      for (int r = 0; r < 9; r++) {
        const float4* rp = (const float4*)&S[hb + r * 12];
        const float4 ra = rp[0], rb = rp[1], rc = rp[2];
        const float row[12] = {ra.x, ra.y, ra.z, ra.w, rb.x, rb.y, rb.z, rb.w,
                               rc.x, rc.y, rc.z, rc.w};
#pragma unroll
        for (int ky = 0; ky < 3; ky++) {
          const int yy = r - ky;                 // compile-time after unroll
          if (yy >= 0 && yy <= 6) {
#pragma unroll
            for (int xx = 0; xx < 7; xx++)
              acc[yy][xx] = fmaf(row[xx],     w[ky * 3 + 0],
                            fmaf(row[xx + 1], w[ky * 3 + 1],
                            fmaf(row[xx + 2], w[ky * 3 + 2], acc[yy][xx])));
          }
        }
      }
    }
    // pair-reduce icg halves within the wave (lane ^ 32)
#pragma unroll
    for (int yy = 0; yy < 7; yy++)
#pragma unroll
      for (int xx = 0; xx < 7; xx++)
        acc[yy][xx] += __shfl_xor(acc[yy][xx], 32, 64);
    __syncthreads();                 // HROW fully consumed; P5 overwrites it
    const int wv = t >> 6;
    if ((t & 63) < 32) {
      float* pp = &S[P5 + (wv * 32 + oc) * 49];
#pragma unroll
      for (int yy = 0; yy < 7; yy++)
#pragma unroll
        for (int xx = 0; xx < 7; xx++)
          pp[yy * 7 + xx] = acc[yy][xx];
    }
  }
  __syncthreads();
  // reduce 4 wave-partials -> C2S [32][7][8] (+bias, lrelu), div-free (R13)
  {
    const int oc = t & 31, yy = t >> 5;   // yy in [0,8)
    if (yy < 7) {
      const float bv = b2[oc];
#pragma unroll
      for (int xx = 0; xx < 7; xx++) {
        const int pos = yy * 7 + xx;
        const float s = bv
            + S[P5 + oc * 49 + pos]        + S[P5 + (32 + oc) * 49 + pos]
            + S[P5 + (64 + oc) * 49 + pos] + S[P5 + (96 + oc) * 49 + pos];
        S[C2S + oc * 56 + yy * 8 + xx] = lrelu(s);
      }
    }
  }
  __syncthreads();

  // ---- stage 6: conv3 32->8 3x3, K split in 8 groups of 4 ic, pw3 f4 loads ----
  {
    const int px = t & 31, ic8 = t >> 5;
    if (px < 25) {
      const int y = px / 5, xx = px - y * 5;
      float p[8] = {0,0,0,0,0,0,0,0};
      const float4* pw34 = (const float4*)pw3;
#pragma unroll
      for (int i = 0; i < 4; i++) {
        const int icg = ic8 * 4 + i;
        float rr[9];
#pragma unroll
        for (int ky = 0; ky < 3; ky++) {
          const int base = C2S + icg * 56 + (y + ky) * 8 + xx;
          rr[ky * 3 + 0] = S[base];
          rr[ky * 3 + 1] = S[base + 1];
          rr[ky * 3 + 2] = S[base + 2];
        }
#pragma unroll
        for (int oc = 0; oc < 8; oc++) {
          const float4 f0 = pw34[(icg * 8 + oc) * 3 + 0];
          const float4 f1 = pw34[(icg * 8 + oc) * 3 + 1];
          const float4 f2 = pw34[(icg * 8 + oc) * 3 + 2];
          p[oc] = fmaf(rr[0], f0.x, fmaf(rr[1], f0.y, fmaf(rr[2], f0.z,
                  fmaf(rr[3], f0.w, fmaf(rr[4], f1.x, fmaf(rr[5], f1.y,
                  fmaf(rr[6], f1.z, fmaf(rr[7], f1.w, fmaf(rr[8], f2.x, p[oc])))))))));
        }
      }
      float* wpp = &S[P6 + px * 64 + ic8 * 8];
#pragma unroll
      for (int oc = 0; oc < 8; oc++) wpp[oc] = p[oc];
    }
  }
  __syncthreads();
  if (t < 200) {
    const int oc = t & 7, px = t >> 3;
    float s = b3[oc];
    const float* rp = &S[P6 + px * 64 + oc];
#pragma unroll
    for (int g = 0; g < 8; g++) s += rp[g * 8];
    S[C3S + oc * 25 + px] = lrelu(s);
  }
  __syncthreads();

  // ---- stage 7: dense 200->64 partials, 4 chunks (56/56/56/32), float4 ----
  {
    const int o = t & 63, chunk = t >> 6;
    const int start = chunk * 56;
    const int cnt = (chunk == 3) ? 8 : 14;
    const float4* wr4 = (const float4*)&dw1[o * 200 + start];
    const float4* cr4 = (const float4*)&S[C3S + start];
    float acc = 0.f;
    for (int i = 0; i < cnt; i++) {   // runtime bound OK: memory only
      const float4 wv = wr4[i], cv = cr4[i];
      acc += wv.x * cv.x + wv.y * cv.y + wv.z * cv.z + wv.w * cv.w;
    }
    S[D1P + chunk * 64 + o] = acc;
  }
  __syncthreads();

  // ---- dense head: wave 0 only, no workgroup barriers (waves 1-3 retire) ----
  if (t < 64) {
    S[D1 + t] = lrelu(S[D1P + t] + S[D1P + 64 + t] + S[D1P + 128 + t] +
                      S[D1P + 192 + t] + db1[t]);
    __builtin_amdgcn_s_waitcnt(0); __builtin_amdgcn_wave_barrier();
    if (t < 32) {
      float acc = db2[t];
      const float4* wr = (const float4*)&dw2[t * 64];
      const float4* dr = (const float4*)&S[D1];
#pragma unroll
      for (int i = 0; i < 16; i++) acc = fma4(wr[i], dr[i], acc);
      S[D2 + t] = lrelu(acc);
    }
    __builtin_amdgcn_s_waitcnt(0); __builtin_amdgcn_wave_barrier();
    if (t < 16) {
      float acc = db3[t];
      const float4* wr = (const float4*)&dw3[t * 32];
      const float4* dr = (const float4*)&S[D2];
#pragma unroll
      for (int i = 0; i < 8; i++) acc = fma4(wr[i], dr[i], acc);
      S[D3 + t] = lrelu(acc);
    }
    __builtin_amdgcn_s_waitcnt(0); __builtin_amdgcn_wave_barrier();
    if (t < 8) {
      float acc = db4[t];
      const float4* wr = (const float4*)&dw4[t * 16];
      const float4* dr = (const float4*)&S[D3];
#pragma unroll
      for (int i = 0; i < 4; i++) acc = fma4(wr[i], dr[i], acc);
      S[D4 + t] = lrelu(acc);
    }
    __builtin_amdgcn_s_waitcnt(0); __builtin_amdgcn_wave_barrier();
    if (t < 2) {
      float acc = db5[t];
      const float4* wr = (const float4*)&dw5[t * 8];
      const float4* dr = (const float4*)&S[D4];
#pragma unroll
      for (int i = 0; i < 2; i++) acc = fma4(wr[i], dr[i], acc);
      out[(size_t)b * 2 + t] = acc;
    }
  }
}

extern "C" void kernel_launch(void* const* d_in, const int* in_sizes, int n_in,
                              void* d_out, int out_size, void* d_ws, size_t ws_size,
                              hipStream_t stream) {
  const float* x   = (const float*)d_in[0];
  const float* w1  = (const float*)d_in[1];
  const float* b1  = (const float*)d_in[2];
  const float* wt  = (const float*)d_in[3];
  const float* bt  = (const float*)d_in[4];
  const float* wp  = (const float*)d_in[5];
  const float* bp  = (const float*)d_in[6];
  const float* wg  = (const float*)d_in[7];
  const float* bg  = (const float*)d_in[8];
  const float* wo  = (const float*)d_in[9];
  const float* bo  = (const float*)d_in[10];
  const float* w2  = (const float*)d_in[11];
  const float* b2  = (const float*)d_in[12];
  const float* w3  = (const float*)d_in[13];
  const float* b3  = (const float*)d_in[14];
  const float* dw1 = (const float*)d_in[15];
  const float* db1 = (const float*)d_in[16];
  const float* dw2 = (const float*)d_in[17];
  const float* db2 = (const float*)d_in[18];
  const float* dw3 = (const float*)d_in[19];
  const float* db3 = (const float*)d_in[20];
  const float* dw4 = (const float*)d_in[21];
  const float* db4 = (const float*)d_in[22];
  const float* dw5 = (const float*)d_in[23];
  const float* db5 = (const float*)d_in[24];

  float* pw = (float*)d_ws;             // pw2: 24576 floats, pw3: 3072 floats
  repack_w23<<<32, 256, 0, stream>>>(w2, w3, pw);
  const float* pw2 = pw;
  const float* pw3 = pw + 24576;

  int B = in_sizes[0] / 121;
  braggnn_fused<<<B, 256, 0, stream>>>(
      x, w1, b1, wt, bt, wp, bp, wg, bg, wo, bo, pw2, pw3, b2, b3,
      dw1, db1, dw2, db2, dw3, db3, dw4, db4, dw5, db5,
      (float*)d_out);
}